// Round 2
// baseline (636.484 us; speedup 1.0000x reference)
//
#include <hip/hip_runtime.h>
#include <hip/hip_bf16.h>

// EfficientLinearAttention on MI355X (gfx950).
// B=8 T=8192 C=512 H=8 D=64.  M = B*T = 65536 rows.
// External tensors fp32, internal compute bf16, output fp32.
//
// Pipeline:
//   memset KV/Ksum
//   cvt_x    : x fp32 -> bf16 xb            (in d_out[0:64MiB))
//   cvt_wb   : Wq/Wk/Wv/Wo + biases -> bf16 Wpack/bpack (ws)
//   qkv_gemm : fused Q/K/V projection, 2-phase dbuf global_load_lds staging
//   kv_reduce: KV[bh] += K^T V (MFMA, 16 T-chunks, fp32 atomics); Ksum folded
//   kv_pack  : KV fp32 -> bf16 in MFMA B-fragment order
//   attn_apply: attn = (Q@KV)/(Q.Ksum+1e-6), in-place on ws.Qb
//   out_gemm : out = attn@Wo^T+bo -> d_out fp32
//
// R5 == R4 resubmit (R4 bench was an infra failure: container never ran).
// R4 changes vs R3-best (596 us):
//   * gemm_core: 2-phase double-buffered LDS (issue next K-tile's DMA before
//     current tile's MFMAs; ONE barrier/step so the vmcnt drain lands after
//     compute).  DMA latency hides under MFMA instead of being serialized.
//   * gemm_core: XOR-swizzled staging (swizzle the GLOBAL source column,
//     un-swizzle on ds_read; DMA dest stays linear as HW requires) ->
//     b128 fragment reads 2-way (free) instead of ~4-8 way.
//   * qkv/out: bijective XCD remap so the blocks sharing an A m-tile run on
//     one XCD (L2 reuse instead of 8x refetch).
//   * qkv/out: LDS-staged epilogue -> 16B/lane coalesced stores (was scalar
//     u16/u32 with 1.6x write amplification).
//   * kv_reduce: 16 T-chunks (1024 blocks) for latency hiding.

typedef unsigned short u16t;
typedef unsigned int   u32t;
typedef __bf16 v8bf __attribute__((ext_vector_type(8)));
typedef u16t   v8u  __attribute__((ext_vector_type(8)));
typedef float  v4f  __attribute__((ext_vector_type(4)));

static __device__ __forceinline__ float bf2f(u16t b) {
    u32t u = ((u32t)b) << 16;
    return __builtin_bit_cast(float, u);
}
static __device__ __forceinline__ u16t f2bf(float f) {
    u32t u = __builtin_bit_cast(u32t, f);
    u += 0x7fffu + ((u >> 16) & 1u);   // round-to-nearest-even
    return (u16t)(u >> 16);
}
static __device__ __forceinline__ v8u cvt8(const float* p) {
    const float4 a = *(const float4*)p;
    const float4 b = *(const float4*)(p + 4);
    v8u r;
    r[0] = f2bf(a.x); r[1] = f2bf(a.y); r[2] = f2bf(a.z); r[3] = f2bf(a.w);
    r[4] = f2bf(b.x); r[5] = f2bf(b.y); r[6] = f2bf(b.z); r[7] = f2bf(b.w);
    return r;
}

// async global->LDS, 16B per lane; LDS dest must be base+lane*16 contiguous.
#define GLDS16(g, l) __builtin_amdgcn_global_load_lds(                       \
        (const __attribute__((address_space(1))) void*)(g),                  \
        (__attribute__((address_space(3))) void*)(l), 16, 0, 0)

// ---------------------------------------------------------------------------
__global__ __launch_bounds__(256) void cvt_x(
        const float* __restrict__ src, u16t* __restrict__ dst) {
    const int i = (blockIdx.x * 256 + threadIdx.x) * 8;   // 16384 blocks
    *(v8u*)&dst[i] = cvt8(&src[i]);
}

__global__ __launch_bounds__(256) void cvt_wb(
        const float* __restrict__ Wq, const float* __restrict__ Wk,
        const float* __restrict__ Wv, const float* __restrict__ Wo,
        const float* __restrict__ bq, const float* __restrict__ bk,
        const float* __restrict__ bv, const float* __restrict__ bo,
        u16t* __restrict__ Wpack, u16t* __restrict__ bpack) {
    const int b = blockIdx.x;
    if (b < 512) {                       // 4 x 512x512 weights, 2048 elems/blk
        const int gidx = (b * 256 + threadIdx.x) * 8;     // [0, 1048576)
        const int seg = gidx >> 18;
        const int off = gidx & 262143;
        const float* src = (seg == 0) ? Wq : (seg == 1) ? Wk
                          : (seg == 2) ? Wv : Wo;
        *(v8u*)&Wpack[gidx] = cvt8(&src[off]);
    } else {                             // 4 biases of 512
        const int seg = b - 512;
        const float* src = (seg == 0) ? bq : (seg == 1) ? bk
                          : (seg == 2) ? bv : bo;
        if (threadIdx.x < 64) {
            const int off = threadIdx.x * 8;
            *(v8u*)&bpack[seg * 512 + off] = cvt8(&src[off]);
        }
    }
}

// ---------------------------------------------------------------------------
// Shared GEMM core: C_tile[128x128] = A[128xK] @ W[128xK]^T, K=512, bf16,
// fp32 accum.  4 waves in 2x2 grid, 64x64 per wave, 4x4 16x16x32 MFMA tiles.
//
// 2-phase double-buffered staging: per K-step, issue the NEXT tile's 4
// global_load_lds (16B/lane) into buf^1, then ds_read + 16 MFMA from buf,
// then a single __syncthreads (drains vmcnt AFTER compute -> overlap).
// LDS layout per buffer: A[128][32], B[128][32], row-major (linear, as the
// DMA requires).  Bank-conflict fix via XOR swizzle applied on the global
// SOURCE column (slot ^= (row>>1)&3, 8-elem slots) and undone on the read:
// fragment ds_read_b128 goes from ~4-way conflict to 2-way (free).
// ---------------------------------------------------------------------------
static __device__ __forceinline__ void gemm_core(
        const u16t* __restrict__ A, const u16t* __restrict__ W,
        size_t mbase, int nbase, u16t* sm, v4f acc[4][4], int tid) {
    const int w    = tid >> 6;
    const int lane = tid & 63;
    const int quad = lane >> 4;
    const int l16  = lane & 15;
    const int wm   = (w & 1) * 64;
    const int wn   = (w >> 1) * 64;

#pragma unroll
    for (int i = 0; i < 4; ++i)
#pragma unroll
        for (int j = 0; j < 4; ++j) acc[i][j] = (v4f){0.f, 0.f, 0.f, 0.f};

    // DMA rows for this thread's two A-issues / two B-issues.
    const int r0 = w * 32 + (lane >> 2);
    const int r1 = r0 + 16;
    // swizzled source k-slot: LDS[r][s] ends up holding G[r][s ^ ((r>>1)&3)]
    // ((r>>1)&3 == (lane>>3)&3 for both r0 and r1).
    const int cs = ((lane & 3) ^ ((lane >> 3) & 3)) * 8;
    const u16t* pa0 = A + (mbase + r0) * 512 + cs;
    const u16t* pa1 = A + (mbase + r1) * 512 + cs;
    const u16t* pb0 = W + (size_t)(nbase + r0) * 512 + cs;
    const u16t* pb1 = W + (size_t)(nbase + r1) * 512 + cs;
    u16t* const la = sm + w * 1024 + lane * 8;          // A dest in buf 0
    u16t* const lb = sm + 8192 + w * 1024 + lane * 8;   // B dest in buf 0

#define GC_ISSUE(buf)                                                        \
    do {                                                                     \
        GLDS16(pa0, la + (buf) * 4096);                                      \
        GLDS16(pa1, la + (buf) * 4096 + 512);                                \
        GLDS16(pb0, lb + (buf) * 4096);                                      \
        GLDS16(pb1, lb + (buf) * 4096 + 512);                                \
        pa0 += 32; pa1 += 32; pb0 += 32; pb1 += 32;                          \
    } while (0)

    GC_ISSUE(0);
    __syncthreads();                     // prologue: tile 0 landed

    const int sA = (quad ^ ((l16 >> 1) & 3)) * 8;   // un-swizzle on read
    int cur = 0;
#pragma unroll
    for (int kt = 0; kt < 16; ++kt) {
        if (kt < 15) GC_ISSUE(cur ^ 1);  // prefetch next tile (async DMA)
        const u16t* Ab = sm + cur * 4096;
        const u16t* Bb = sm + 8192 + cur * 4096;
        v8bf af[4], bfr[4];
#pragma unroll
        for (int mi = 0; mi < 4; ++mi)
            af[mi] = *(const v8bf*)&Ab[(wm + mi * 16 + l16) * 32 + sA];
#pragma unroll
        for (int ni = 0; ni < 4; ++ni)
            bfr[ni] = *(const v8bf*)&Bb[(wn + ni * 16 + l16) * 32 + sA];
#pragma unroll
        for (int mi = 0; mi < 4; ++mi)
#pragma unroll
            for (int ni = 0; ni < 4; ++ni)
                acc[mi][ni] = __builtin_amdgcn_mfma_f32_16x16x32_bf16(
                    af[mi], bfr[ni], acc[mi][ni], 0, 0, 0);
        __syncthreads();                 // drains vmcnt: prefetch landed
        cur ^= 1;
    }
#undef GC_ISSUE
}

// Fused Q/K/V projection.  1-D grid of 6144 blocks, XCD-bijective remap:
// wg = (id%8)*768 + id/8 -> each XCD owns 64 contiguous m-tiles and the 12
// (p,n)-blocks of one m-tile are consecutive on that XCD (A-tile L2 reuse).
__global__ __launch_bounds__(256) void qkv_gemm(
        const u16t* __restrict__ xb, const u16t* __restrict__ Wpack,
        const u16t* __restrict__ bpack,
        u16t* __restrict__ Qb, u16t* __restrict__ Kb, u16t* __restrict__ Vb) {
    __shared__ __align__(16) u16t sm[16896];   // staging 32KiB | Cs[128][132]
    const u32t id = blockIdx.x;
    const u32t wg = (id & 7) * 768 + (id >> 3);
    const int sub = (int)(wg % 12u);
    const int p = sub >> 2;
    const int nbase = (sub & 3) * 128;
    const size_t mbase = (size_t)(wg / 12u) * 128;
    const u16t* W = Wpack + (size_t)p * 262144;
    const u16t* bias = bpack + p * 512;
    u16t* C = (p == 0) ? Qb : (p == 1) ? Kb : Vb;
    const bool elu = (p < 2);
    const int tid = threadIdx.x;
    const int w = tid >> 6, lane = tid & 63, quad = lane >> 4, l16 = lane & 15;
    const int wm = (w & 1) * 64, wn = (w >> 1) * 64;

    v4f acc[4][4];
    gemm_core(xb, W, mbase, nbase, sm, acc, tid);

    // Epilogue: bias+ELU in regs, stage bf16 tile in LDS [128][132]
    // (132 pad -> 2-way-free b16 writes), re-read row-major, 16B stores.
    u16t (*Cs)[132] = (u16t(*)[132])sm;
#pragma unroll
    for (int ni = 0; ni < 4; ++ni) {
        const int lcol = wn + ni * 16 + l16;
        const float bb = bf2f(bias[nbase + lcol]);
#pragma unroll
        for (int mi = 0; mi < 4; ++mi)
#pragma unroll
            for (int r = 0; r < 4; ++r) {
                const int lrow = wm + mi * 16 + quad * 4 + r;
                float v = acc[mi][ni][r] + bb;
                if (elu) v = (v > 0.f) ? (v + 1.f) : __expf(v);   // elu(x)+1
                Cs[lrow][lcol] = f2bf(v);
            }
    }
    __syncthreads();
#pragma unroll
    for (int rep = 0; rep < 8; ++rep) {
        const int f = rep * 256 + tid;       // [0,2048): 128 rows x 16 slots
        const int row = f >> 4;
        const int c8 = (f & 15) * 8;
        const uint2 lo = *(const uint2*)&Cs[row][c8];
        const uint2 hi = *(const uint2*)&Cs[row][c8 + 4];
        const uint4 val = make_uint4(lo.x, lo.y, hi.x, hi.y);
        *(uint4*)&C[(mbase + row) * 512 + nbase + c8] = val;
    }
}

// out = attn @ Wo^T + bo, fp32 out.  1-D grid of 2048 blocks, XCD remap.
__global__ __launch_bounds__(256) void out_gemm(
        const u16t* __restrict__ attn, const u16t* __restrict__ Wo,
        const u16t* __restrict__ bo, float* __restrict__ C) {
    __shared__ __align__(16) u16t sm[16896];   // staging | Cf[64][132] fp32
    const u32t id = blockIdx.x;
    const u32t wg = (id & 7) * 256 + (id >> 3);
    const int nbase = (int)(wg & 3u) * 128;
    const size_t mbase = (size_t)(wg >> 2) * 128;
    const int tid = threadIdx.x;
    const int w = tid >> 6, lane = tid & 63, quad = lane >> 4, l16 = lane & 15;
    const int wn = (w >> 1) * 64;

    v4f acc[4][4];
    gemm_core(attn, Wo, mbase, nbase, sm, acc, tid);

    // fp32 tile is 64KiB; stage + store in two 64-row passes of 32KiB.
    float (*Cf)[132] = (float(*)[132])sm;
#pragma unroll
    for (int pass = 0; pass < 2; ++pass) {
        if ((w & 1) == pass) {           // waves owning rows [pass*64, +64)
#pragma unroll
            for (int ni = 0; ni < 4; ++ni) {
                const int lcol = wn + ni * 16 + l16;
                const float bb = bf2f(bo[nbase + lcol]);
#pragma unroll
                for (int mi = 0; mi < 4; ++mi)
#pragma unroll
                    for (int r = 0; r < 4; ++r)
                        Cf[mi * 16 + quad * 4 + r][lcol] = acc[mi][ni][r] + bb;
            }
        }
        __syncthreads();
#pragma unroll
        for (int rep = 0; rep < 8; ++rep) {
            const int f = rep * 256 + tid;   // [0,2048): 64 rows x 32 f4slots
            const int row = f >> 5;
            const int c4 = (f & 31) * 4;
            const float4 v = *(const float4*)&Cf[row][c4];
            *(float4*)&C[(mbase + pass * 64 + row) * 512 + nbase + c4] = v;
        }
        __syncthreads();
    }
}

// ---------------------------------------------------------------------------
// KV[bh][d][e] = sum_t K[t][d]*V[t][e];  Ksum[bh][d] = sum_t K[t][d].
// grid (64 bh, 16 T-chunks), block 256.
// ---------------------------------------------------------------------------
__global__ __launch_bounds__(256) void kv_reduce(
        const u16t* __restrict__ Kp, const u16t* __restrict__ Vp,
        float* __restrict__ KV, float* __restrict__ Ksum) {
    __shared__ u16t Kl[64][66];
    __shared__ u16t Vl[64][66];
    const int bh = blockIdx.x;
    const int chunk = blockIdx.y;
    const int b = bh >> 3, h = bh & 7;
    const int tid = threadIdx.x;
    const int w = tid >> 6, lane = tid & 63, quad = lane >> 4, l16 = lane & 15;
    const int trow0 = tid >> 3;
    const int c8 = (tid & 7) * 8;
    const size_t rowbase = (size_t)b * 8192;

    v4f acc[4];
#pragma unroll
    for (int i = 0; i < 4; ++i) acc[i] = (v4f){0.f, 0.f, 0.f, 0.f};
    float ks[8];
#pragma unroll
    for (int j = 0; j < 8; ++j) ks[j] = 0.f;

    for (int tile = 0; tile < 8; ++tile) {
        const int t0 = chunk * 512 + tile * 64;
#pragma unroll
        for (int i = 0; i < 2; ++i) {
            const int trow = trow0 + i * 32;
            const size_t goff = (rowbase + t0 + trow) * 512 + h * 64 + c8;
            const uint4 kq = *(const uint4*)&Kp[goff];
            const uint4 vq = *(const uint4*)&Vp[goff];
            *(u32t*)&Kl[trow][c8 + 0] = kq.x;
            *(u32t*)&Kl[trow][c8 + 2] = kq.y;
            *(u32t*)&Kl[trow][c8 + 4] = kq.z;
            *(u32t*)&Kl[trow][c8 + 6] = kq.w;
            *(u32t*)&Vl[trow][c8 + 0] = vq.x;
            *(u32t*)&Vl[trow][c8 + 2] = vq.y;
            *(u32t*)&Vl[trow][c8 + 4] = vq.z;
            *(u32t*)&Vl[trow][c8 + 6] = vq.w;
            const v8u ku = __builtin_bit_cast(v8u, kq);
#pragma unroll
            for (int j = 0; j < 8; ++j) ks[j] += bf2f(ku[j]);
        }
        __syncthreads();
#pragma unroll
        for (int ts = 0; ts < 2; ++ts) {
            v8u au;
#pragma unroll
            for (int j = 0; j < 8; ++j)
                au[j] = Kl[ts * 32 + quad * 8 + j][w * 16 + l16];
            const v8bf af = __builtin_bit_cast(v8bf, au);
#pragma unroll
            for (int et = 0; et < 4; ++et) {
                v8u bu;
#pragma unroll
                for (int j = 0; j < 8; ++j)
                    bu[j] = Vl[ts * 32 + quad * 8 + j][et * 16 + l16];
                acc[et] = __builtin_amdgcn_mfma_f32_16x16x32_bf16(
                    af, __builtin_bit_cast(v8bf, bu), acc[et], 0, 0, 0);
            }
        }
        __syncthreads();
    }

#pragma unroll
    for (int et = 0; et < 4; ++et)
#pragma unroll
        for (int r = 0; r < 4; ++r) {
            const int d = w * 16 + quad * 4 + r;
            const int e = et * 16 + l16;
            atomicAdd(&KV[((size_t)bh * 64 + d) * 64 + e], acc[et][r]);
        }
#pragma unroll
    for (int j = 0; j < 8; ++j)
        atomicAdd(&Ksum[bh * 64 + c8 + j], ks[j]);
}

// fp32 KV[bh][64][64] -> bf16 in MFMA B-fragment order.
__global__ __launch_bounds__(256) void kv_pack(
        const float* __restrict__ KV, u16t* __restrict__ KVb) {
    const int bh = blockIdx.x;
    const int tid = threadIdx.x;
#pragma unroll
    for (int i = 0; i < 2; ++i) {
        const int c = tid + i * 256;
        const int ksi = c >> 8;
        const int nb = (c >> 6) & 3;
        const int L = c & 63;
        const int quad = L >> 4, l16 = L & 15;
        v8u pk;
#pragma unroll
        for (int j = 0; j < 8; ++j) {
            const int d = ksi * 32 + quad * 8 + j;
            const int e = nb * 16 + l16;
            pk[j] = f2bf(KV[((size_t)bh * 64 + d) * 64 + e]);
        }
        *(v8u*)&KVb[((size_t)bh * 512 + c) * 8] = pk;
    }
}

// attn = (Q @ KV) / (Q.Ksum + 1e-6), in-place over Q.  grid (512, 8).
__global__ __launch_bounds__(256) void attn_apply(
        u16t* __restrict__ Q, const u16t* __restrict__ KVb,
        const float* __restrict__ Ksum) {
    __shared__ u16t Qs[128][72];
    __shared__ float ksl[64];
    __shared__ float rden[128];
    const int bx = blockIdx.x;
    const int h = blockIdx.y;
    const int b = bx >> 6;
    const int bh = b * 8 + h;
    const int tid = threadIdx.x;
    const int w = tid >> 6, lane = tid & 63, quad = lane >> 4, l16 = lane & 15;
    const size_t row0 = (size_t)bx * 128;

#pragma unroll
    for (int i = 0; i < 4; ++i) {
        const int cid = tid + i * 256;
        const int r = cid >> 3;
        const int c8 = (cid & 7) * 8;
        *(uint4*)&Qs[r][c8] = *(const uint4*)&Q[(row0 + r) * 512 + h * 64 + c8];
    }
    if (tid < 64) ksl[tid] = Ksum[bh * 64 + tid];
    __syncthreads();

    if (tid < 128) {
        float a = 1e-6f;
#pragma unroll
        for (int d = 0; d < 64; ++d) a += bf2f(Qs[tid][d]) * ksl[d];
        rden[tid] = 1.0f / fmaxf(a, 1e-9f);
    }

    v8bf bfr[2][4];
#pragma unroll
    for (int ksi = 0; ksi < 2; ++ksi)
#pragma unroll
        for (int nb = 0; nb < 4; ++nb)
            bfr[ksi][nb] = *(const v8bf*)
                &KVb[((size_t)bh * 512 + ksi * 256 + nb * 64 + lane) * 8];
    __syncthreads();

    v4f acc[2][4];
#pragma unroll
    for (int i = 0; i < 2; ++i)
#pragma unroll
        for (int j = 0; j < 4; ++j) acc[i][j] = (v4f){0.f, 0.f, 0.f, 0.f};

#pragma unroll
    for (int ksi = 0; ksi < 2; ++ksi) {
        v8bf af[2];
#pragma unroll
        for (int mt = 0; mt < 2; ++mt)
            af[mt] = *(const v8bf*)&Qs[w * 32 + mt * 16 + l16][ksi * 32 + quad * 8];
#pragma unroll
        for (int mt = 0; mt < 2; ++mt)
#pragma unroll
            for (int nb = 0; nb < 4; ++nb)
                acc[mt][nb] = __builtin_amdgcn_mfma_f32_16x16x32_bf16(
                    af[mt], bfr[ksi][nb], acc[mt][nb], 0, 0, 0);
    }

#pragma unroll
    for (int mt = 0; mt < 2; ++mt)
#pragma unroll
        for (int nb = 0; nb < 4; ++nb)
#pragma unroll
            for (int r = 0; r < 4; ++r) {
                const int rl = w * 32 + mt * 16 + quad * 4 + r;
                const int e = nb * 16 + l16;
                const float v = acc[mt][nb][r] * rden[rl];
                Q[(row0 + rl) * 512 + h * 64 + e] = f2bf(v);
            }
}

// ---------------------------------------------------------------------------
extern "C" void kernel_launch(void* const* d_in, const int* in_sizes, int n_in,
                              void* d_out, int out_size, void* d_ws, size_t ws_size,
                              hipStream_t stream) {
    (void)in_sizes; (void)n_in; (void)out_size; (void)ws_size;
    const float* x32  = (const float*)d_in[0];
    const float* Wq32 = (const float*)d_in[1];
    const float* bq32 = (const float*)d_in[2];
    const float* Wk32 = (const float*)d_in[3];
    const float* bk32 = (const float*)d_in[4];
    const float* Wv32 = (const float*)d_in[5];
    const float* bv32 = (const float*)d_in[6];
    const float* Wo32 = (const float*)d_in[7];
    const float* bo32 = (const float*)d_in[8];

    // d_out (128 MiB fp32) doubles as scratch: xb bf16 + Vb bf16.
    u16t* xb = (u16t*)d_out;
    u16t* Vb = (u16t*)d_out + (size_t)33554432;

    char* ws = (char*)d_ws;
    const size_t SZ   = (size_t)65536 * 512 * sizeof(u16t);    // 64 MiB
    const size_t KVB  = (size_t)64 * 64 * 64 * 4;              // 1 MiB
    const size_t KSB  = (size_t)64 * 64 * 4;                   // 16 KiB
    const size_t KVbB = (size_t)64 * 512 * 16;                 // 512 KiB
    u16t*  Qb    = (u16t*)(ws);
    u16t*  Kb    = (u16t*)(ws + SZ);
    float* KV    = (float*)(ws + 2 * SZ);
    float* Ks    = (float*)(ws + 2 * SZ + KVB);
    u16t*  KVb   = (u16t*)(ws + 2 * SZ + KVB + KSB);
    u16t*  Wpack = (u16t*)(ws + 2 * SZ + KVB + KSB + KVbB);
    u16t*  bpack = Wpack + (size_t)4 * 262144;

    hipMemsetAsync(KV, 0, KVB + KSB, stream);

    const dim3 blk(256);
    cvt_x <<<dim3(16384), blk, 0, stream>>>(x32, xb);
    cvt_wb<<<dim3(516),   blk, 0, stream>>>(Wq32, Wk32, Wv32, Wo32,
                                            bq32, bk32, bv32, bo32,
                                            Wpack, bpack);
    qkv_gemm  <<<dim3(6144),   blk, 0, stream>>>(xb, Wpack, bpack, Qb, Kb, Vb);
    kv_reduce <<<dim3(64, 16), blk, 0, stream>>>(Kb, Vb, KV, Ks);
    kv_pack   <<<dim3(64),     blk, 0, stream>>>(KV, KVb);
    attn_apply<<<dim3(512, 8), blk, 0, stream>>>(Qb, KVb, Ks);
    out_gemm  <<<dim3(2048),   blk, 0, stream>>>(Qb, Wpack + 3 * 262144,
                                                 bpack + 3 * 512,
                                                 (float*)d_out);
}

// Round 3
// 511.037 us; speedup vs baseline: 1.2455x; 1.2455x over previous
//
#include <hip/hip_runtime.h>
#include <hip/hip_bf16.h>

// EfficientLinearAttention on MI355X (gfx950).
// B=8 T=8192 C=512 H=8 D=64.  M = B*T = 65536 rows.
// External tensors fp32, internal compute bf16, output fp32.
//
// Pipeline:
//   cvt_x    : x fp32 -> bf16 xb            (in d_out[0:64MiB))
//   cvt_wb   : Wq/Wk/Wv/Wo + biases -> bf16 Wpack/bpack (ws)
//   qkv_gemm : fused Q/K/V projection, 2-phase dbuf global_load_lds staging
//   kv_reduce: per-(bh,chunk) partial KV = K^T V + Ksum partial, NO atomics
//              (partials into d_out[0:17MB), dead xb region)
//   kv_pack  : fold 16 chunk-partials, write Ks + bf16 KVb fragments
//   attn_apply: attn = (Q@KV)/(Q.Ksum+1e-6), in-place on ws.Qb
//   out_gemm : out = attn@Wo^T+bo -> d_out fp32
//
// R5 changes vs R4 (636 us, kv_reduce 187 us = #1):
//   * kv_reduce: atomics REMOVED (R4's 6.3M device-scope RMWs -> WRITE_SIZE
//     80MiB and 187us at 0.9% MfmaUtil).  Each block stores a private
//     65x64 fp32 partial (row 64 = Ksum partial, LDS-tree reduced).
//   * kv_reduce: XCD-bijective remap (batch b -> XCD b; 8 h-blocks of one
//     (b,chunk) adjacent -> the 8x128B column slices of each 1KiB row are
//     read together).  Register prefetch of next tile issued during the
//     MFMA phase so the barrier vmcnt-drain is covered by compute.
//   * kv_pack: folds the 16-chunk reduction (coalesced float4) + Ksum.
//   * qkv/out epilogue: half-tile passes -> block LDS 33792->32768 B
//     (5 blocks/CU instead of 4).
//   * attn_apply: epilogue restaged through LDS -> uint4 stores (was 32
//     scalar u16 global stores per thread).

typedef unsigned short u16t;
typedef unsigned int   u32t;
typedef __bf16 v8bf __attribute__((ext_vector_type(8)));
typedef u16t   v8u  __attribute__((ext_vector_type(8)));
typedef float  v4f  __attribute__((ext_vector_type(4)));

static __device__ __forceinline__ float bf2f(u16t b) {
    u32t u = ((u32t)b) << 16;
    return __builtin_bit_cast(float, u);
}
static __device__ __forceinline__ u16t f2bf(float f) {
    u32t u = __builtin_bit_cast(u32t, f);
    u += 0x7fffu + ((u >> 16) & 1u);   // round-to-nearest-even
    return (u16t)(u >> 16);
}
static __device__ __forceinline__ v8u cvt8(const float* p) {
    const float4 a = *(const float4*)p;
    const float4 b = *(const float4*)(p + 4);
    v8u r;
    r[0] = f2bf(a.x); r[1] = f2bf(a.y); r[2] = f2bf(a.z); r[3] = f2bf(a.w);
    r[4] = f2bf(b.x); r[5] = f2bf(b.y); r[6] = f2bf(b.z); r[7] = f2bf(b.w);
    return r;
}

// async global->LDS, 16B per lane; LDS dest must be base+lane*16 contiguous.
#define GLDS16(g, l) __builtin_amdgcn_global_load_lds(                       \
        (const __attribute__((address_space(1))) void*)(g),                  \
        (__attribute__((address_space(3))) void*)(l), 16, 0, 0)

// ---------------------------------------------------------------------------
__global__ __launch_bounds__(256) void cvt_x(
        const float* __restrict__ src, u16t* __restrict__ dst) {
    const int i = (blockIdx.x * 256 + threadIdx.x) * 8;   // 16384 blocks
    *(v8u*)&dst[i] = cvt8(&src[i]);
}

__global__ __launch_bounds__(256) void cvt_wb(
        const float* __restrict__ Wq, const float* __restrict__ Wk,
        const float* __restrict__ Wv, const float* __restrict__ Wo,
        const float* __restrict__ bq, const float* __restrict__ bk,
        const float* __restrict__ bv, const float* __restrict__ bo,
        u16t* __restrict__ Wpack, u16t* __restrict__ bpack) {
    const int b = blockIdx.x;
    if (b < 512) {                       // 4 x 512x512 weights, 2048 elems/blk
        const int gidx = (b * 256 + threadIdx.x) * 8;     // [0, 1048576)
        const int seg = gidx >> 18;
        const int off = gidx & 262143;
        const float* src = (seg == 0) ? Wq : (seg == 1) ? Wk
                          : (seg == 2) ? Wv : Wo;
        *(v8u*)&Wpack[gidx] = cvt8(&src[off]);
    } else {                             // 4 biases of 512
        const int seg = b - 512;
        const float* src = (seg == 0) ? bq : (seg == 1) ? bk
                          : (seg == 2) ? bv : bo;
        if (threadIdx.x < 64) {
            const int off = threadIdx.x * 8;
            *(v8u*)&bpack[seg * 512 + off] = cvt8(&src[off]);
        }
    }
}

// ---------------------------------------------------------------------------
// Shared GEMM core: C_tile[128x128] = A[128xK] @ W[128xK]^T, K=512, bf16,
// fp32 accum.  4 waves in 2x2 grid, 64x64 per wave, 4x4 16x16x32 MFMA tiles.
//
// 2-phase double-buffered staging: per K-step, issue the NEXT tile's 4
// global_load_lds (16B/lane) into buf^1, then ds_read + 16 MFMA from buf,
// then a single __syncthreads (drains vmcnt AFTER compute -> overlap).
// Bank-conflict fix via XOR swizzle applied on the global SOURCE column
// (slot ^= (row>>1)&3) and undone on the ds_read side (dest stays linear
// as the DMA requires).
// ---------------------------------------------------------------------------
static __device__ __forceinline__ void gemm_core(
        const u16t* __restrict__ A, const u16t* __restrict__ W,
        size_t mbase, int nbase, u16t* sm, v4f acc[4][4], int tid) {
    const int w    = tid >> 6;
    const int lane = tid & 63;
    const int quad = lane >> 4;
    const int l16  = lane & 15;
    const int wm   = (w & 1) * 64;
    const int wn   = (w >> 1) * 64;

#pragma unroll
    for (int i = 0; i < 4; ++i)
#pragma unroll
        for (int j = 0; j < 4; ++j) acc[i][j] = (v4f){0.f, 0.f, 0.f, 0.f};

    // DMA rows for this thread's two A-issues / two B-issues.
    const int r0 = w * 32 + (lane >> 2);
    const int r1 = r0 + 16;
    // swizzled source k-slot: LDS[r][s] ends up holding G[r][s ^ ((r>>1)&3)]
    // ((r>>1)&3 == (lane>>3)&3 for both r0 and r1).
    const int cs = ((lane & 3) ^ ((lane >> 3) & 3)) * 8;
    const u16t* pa0 = A + (mbase + r0) * 512 + cs;
    const u16t* pa1 = A + (mbase + r1) * 512 + cs;
    const u16t* pb0 = W + (size_t)(nbase + r0) * 512 + cs;
    const u16t* pb1 = W + (size_t)(nbase + r1) * 512 + cs;
    u16t* const la = sm + w * 1024 + lane * 8;          // A dest in buf 0
    u16t* const lb = sm + 8192 + w * 1024 + lane * 8;   // B dest in buf 0

#define GC_ISSUE(buf)                                                        \
    do {                                                                     \
        GLDS16(pa0, la + (buf) * 4096);                                      \
        GLDS16(pa1, la + (buf) * 4096 + 512);                                \
        GLDS16(pb0, lb + (buf) * 4096);                                      \
        GLDS16(pb1, lb + (buf) * 4096 + 512);                                \
        pa0 += 32; pa1 += 32; pb0 += 32; pb1 += 32;                          \
    } while (0)

    GC_ISSUE(0);
    __syncthreads();                     // prologue: tile 0 landed

    const int sA = (quad ^ ((l16 >> 1) & 3)) * 8;   // un-swizzle on read
    int cur = 0;
#pragma unroll
    for (int kt = 0; kt < 16; ++kt) {
        if (kt < 15) GC_ISSUE(cur ^ 1);  // prefetch next tile (async DMA)
        const u16t* Ab = sm + cur * 4096;
        const u16t* Bb = sm + 8192 + cur * 4096;
        v8bf af[4], bfr[4];
#pragma unroll
        for (int mi = 0; mi < 4; ++mi)
            af[mi] = *(const v8bf*)&Ab[(wm + mi * 16 + l16) * 32 + sA];
#pragma unroll
        for (int ni = 0; ni < 4; ++ni)
            bfr[ni] = *(const v8bf*)&Bb[(wn + ni * 16 + l16) * 32 + sA];
#pragma unroll
        for (int mi = 0; mi < 4; ++mi)
#pragma unroll
            for (int ni = 0; ni < 4; ++ni)
                acc[mi][ni] = __builtin_amdgcn_mfma_f32_16x16x32_bf16(
                    af[mi], bfr[ni], acc[mi][ni], 0, 0, 0);
        __syncthreads();                 // drains vmcnt: prefetch landed
        cur ^= 1;
    }
#undef GC_ISSUE
}

// Fused Q/K/V projection.  1-D grid of 6144 blocks, XCD-bijective remap:
// wg = (id%8)*768 + id/8 -> each XCD owns 64 contiguous m-tiles and the 12
// (p,n)-blocks of one m-tile are consecutive on that XCD (A-tile L2 reuse).
__global__ __launch_bounds__(256) void qkv_gemm(
        const u16t* __restrict__ xb, const u16t* __restrict__ Wpack,
        const u16t* __restrict__ bpack,
        u16t* __restrict__ Qb, u16t* __restrict__ Kb, u16t* __restrict__ Vb) {
    __shared__ __align__(16) u16t sm[16384];   // staging 32KiB / Cs[64][132]
    const u32t id = blockIdx.x;
    const u32t wg = (id & 7) * 768 + (id >> 3);
    const int sub = (int)(wg % 12u);
    const int p = sub >> 2;
    const int nbase = (sub & 3) * 128;
    const size_t mbase = (size_t)(wg / 12u) * 128;
    const u16t* W = Wpack + (size_t)p * 262144;
    const u16t* bias = bpack + p * 512;
    u16t* C = (p == 0) ? Qb : (p == 1) ? Kb : Vb;
    const bool elu = (p < 2);
    const int tid = threadIdx.x;
    const int w = tid >> 6, lane = tid & 63, quad = lane >> 4, l16 = lane & 15;
    const int wn = (w >> 1) * 64;

    v4f acc[4][4];
    gemm_core(xb, W, mbase, nbase, sm, acc, tid);

    // Epilogue: two 64-row passes through LDS -> 16B/lane coalesced stores.
    u16t (*Cs)[132] = (u16t(*)[132])sm;
#pragma unroll
    for (int pass = 0; pass < 2; ++pass) {
        if ((w & 1) == pass) {           // waves owning rows [pass*64, +64)
#pragma unroll
            for (int ni = 0; ni < 4; ++ni) {
                const int lcol = wn + ni * 16 + l16;
                const float bb = bf2f(bias[nbase + lcol]);
#pragma unroll
                for (int mi = 0; mi < 4; ++mi)
#pragma unroll
                    for (int r = 0; r < 4; ++r) {
                        float v = acc[mi][ni][r] + bb;
                        if (elu) v = (v > 0.f) ? (v + 1.f) : __expf(v);
                        Cs[mi * 16 + quad * 4 + r][lcol] = f2bf(v);
                    }
            }
        }
        __syncthreads();
#pragma unroll
        for (int rep = 0; rep < 4; ++rep) {
            const int f = rep * 256 + tid;   // [0,1024): 64 rows x 16 8-slots
            const int row = f >> 4;
            const int c8 = (f & 15) * 8;
            const uint2 lo = *(const uint2*)&Cs[row][c8];
            const uint2 hi = *(const uint2*)&Cs[row][c8 + 4];
            const uint4 val = make_uint4(lo.x, lo.y, hi.x, hi.y);
            *(uint4*)&C[(mbase + pass * 64 + row) * 512 + nbase + c8] = val;
        }
        __syncthreads();
    }
}

// out = attn @ Wo^T + bo, fp32 out.  1-D grid of 2048 blocks, XCD remap.
__global__ __launch_bounds__(256) void out_gemm(
        const u16t* __restrict__ attn, const u16t* __restrict__ Wo,
        const u16t* __restrict__ bo, float* __restrict__ C) {
    __shared__ __align__(16) u16t sm[16384];   // staging / Cf[32][132] fp32
    const u32t id = blockIdx.x;
    const u32t wg = (id & 7) * 256 + (id >> 3);
    const int nbase = (int)(wg & 3u) * 128;
    const size_t mbase = (size_t)(wg >> 2) * 128;
    const int tid = threadIdx.x;
    const int w = tid >> 6, lane = tid & 63, quad = lane >> 4, l16 = lane & 15;
    const int wn = (w >> 1) * 64;

    v4f acc[4][4];
    gemm_core(attn, Wo, mbase, nbase, sm, acc, tid);

    // fp32 tile staged + stored in four 32-row passes of 16.5KiB.
    float (*Cf)[132] = (float(*)[132])sm;
#pragma unroll
    for (int p = 0; p < 4; ++p) {
        if ((w & 1) == (p >> 1)) {       // waves owning rows [p*32, +32)
#pragma unroll
            for (int ni = 0; ni < 4; ++ni) {
                const int lcol = wn + ni * 16 + l16;
                const float bb = bf2f(bo[nbase + lcol]);
#pragma unroll
                for (int m2 = 0; m2 < 2; ++m2) {
                    const int mi = (p & 1) * 2 + m2;
#pragma unroll
                    for (int r = 0; r < 4; ++r)
                        Cf[m2 * 16 + quad * 4 + r][lcol] = acc[mi][ni][r] + bb;
                }
            }
        }
        __syncthreads();
#pragma unroll
        for (int rep = 0; rep < 4; ++rep) {
            const int f = rep * 256 + tid;   // [0,1024): 32 rows x 32 f4slots
            const int row = f >> 5;
            const int c4 = (f & 31) * 4;
            *(float4*)&C[(mbase + p * 32 + row) * 512 + nbase + c4] =
                *(const float4*)&Cf[row][c4];
        }
        __syncthreads();
    }
}

// ---------------------------------------------------------------------------
// Partial KV: Part[bh*16+chunk] = [65][64] fp32; rows 0..63 = K^T V over the
// chunk's 512 t-rows, row 64 = Ksum partial.  NO atomics.
// 1-D grid 1024 blocks, XCD-bijective remap: batch b -> XCD b, the 8
// h-blocks of one (b,chunk) adjacent in dispatch (row locality).
// ---------------------------------------------------------------------------
__global__ __launch_bounds__(256) void kv_reduce(
        const u16t* __restrict__ Kp, const u16t* __restrict__ Vp,
        float* __restrict__ Part) {
    __shared__ u16t Kl[64][66];
    __shared__ u16t Vl[64][66];
    const u32t id  = blockIdx.x;                   // [0,1024)
    const u32t swz = (id & 7) * 128 + (id >> 3);   // bijective
    const int h     = (int)(swz & 7);
    const int grp   = (int)(swz >> 3);             // b*16 + chunk
    const int b     = grp >> 4;
    const int chunk = grp & 15;
    const int bh    = b * 8 + h;
    const int tid = threadIdx.x;
    const int w = tid >> 6, lane = tid & 63, quad = lane >> 4, l16 = lane & 15;
    const int trow0 = tid >> 3;                    // 0..31
    const int c8 = (tid & 7) * 8;

    v4f acc[4];
#pragma unroll
    for (int i = 0; i < 4; ++i) acc[i] = (v4f){0.f, 0.f, 0.f, 0.f};
    float ks[8];
#pragma unroll
    for (int j = 0; j < 8; ++j) ks[j] = 0.f;

    size_t g0 = ((size_t)b * 8192 + chunk * 512 + trow0) * 512 + h * 64 + c8;
    size_t g1 = g0 + 32 * 512;
    uint4 kq0 = *(const uint4*)&Kp[g0];
    uint4 kq1 = *(const uint4*)&Kp[g1];
    uint4 vq0 = *(const uint4*)&Vp[g0];
    uint4 vq1 = *(const uint4*)&Vp[g1];

    for (int tile = 0; tile < 8; ++tile) {
        // stage current regs to LDS, fold Ksum
        *(u32t*)&Kl[trow0][c8 + 0] = kq0.x;
        *(u32t*)&Kl[trow0][c8 + 2] = kq0.y;
        *(u32t*)&Kl[trow0][c8 + 4] = kq0.z;
        *(u32t*)&Kl[trow0][c8 + 6] = kq0.w;
        *(u32t*)&Kl[trow0 + 32][c8 + 0] = kq1.x;
        *(u32t*)&Kl[trow0 + 32][c8 + 2] = kq1.y;
        *(u32t*)&Kl[trow0 + 32][c8 + 4] = kq1.z;
        *(u32t*)&Kl[trow0 + 32][c8 + 6] = kq1.w;
        *(u32t*)&Vl[trow0][c8 + 0] = vq0.x;
        *(u32t*)&Vl[trow0][c8 + 2] = vq0.y;
        *(u32t*)&Vl[trow0][c8 + 4] = vq0.z;
        *(u32t*)&Vl[trow0][c8 + 6] = vq0.w;
        *(u32t*)&Vl[trow0 + 32][c8 + 0] = vq1.x;
        *(u32t*)&Vl[trow0 + 32][c8 + 2] = vq1.y;
        *(u32t*)&Vl[trow0 + 32][c8 + 4] = vq1.z;
        *(u32t*)&Vl[trow0 + 32][c8 + 6] = vq1.w;
        {
            const v8u ku0 = __builtin_bit_cast(v8u, kq0);
            const v8u ku1 = __builtin_bit_cast(v8u, kq1);
#pragma unroll
            for (int j = 0; j < 8; ++j)
                ks[j] += bf2f(ku0[j]) + bf2f(ku1[j]);
        }
        __syncthreads();
        // issue next tile's loads now: the end-of-tile barrier's vmcnt
        // drain is then covered by the LDS-read + MFMA phase below.
        if (tile < 7) {
            g0 += 64 * 512; g1 += 64 * 512;
            kq0 = *(const uint4*)&Kp[g0];
            kq1 = *(const uint4*)&Kp[g1];
            vq0 = *(const uint4*)&Vp[g0];
            vq1 = *(const uint4*)&Vp[g1];
        }
#pragma unroll
        for (int ts = 0; ts < 2; ++ts) {
            v8u au;
#pragma unroll
            for (int j = 0; j < 8; ++j)
                au[j] = Kl[ts * 32 + quad * 8 + j][w * 16 + l16];
            const v8bf af = __builtin_bit_cast(v8bf, au);
#pragma unroll
            for (int et = 0; et < 4; ++et) {
                v8u bu;
#pragma unroll
                for (int j = 0; j < 8; ++j)
                    bu[j] = Vl[ts * 32 + quad * 8 + j][et * 16 + l16];
                acc[et] = __builtin_amdgcn_mfma_f32_16x16x32_bf16(
                    af, __builtin_bit_cast(v8bf, bu), acc[et], 0, 0, 0);
            }
        }
        __syncthreads();
    }

    // store partial KV tile (plain coalesced stores)
    const size_t pbase = (size_t)(bh * 16 + chunk) * 4160;   // 65*64
#pragma unroll
    for (int et = 0; et < 4; ++et)
#pragma unroll
        for (int r = 0; r < 4; ++r)
            Part[pbase + (size_t)(w * 16 + quad * 4 + r) * 64 + et * 16 + l16]
                = acc[et][r];

    // Ksum partial: LDS tree (reuse Kl as float [32][65], 8320B <= 8448B)
    float* kr = (float*)&Kl[0][0];
#pragma unroll
    for (int j = 0; j < 8; ++j) kr[trow0 * 65 + c8 + j] = ks[j];
    __syncthreads();
    if (tid < 64) {
        float s = 0.f;
#pragma unroll
        for (int g = 0; g < 32; ++g) s += kr[g * 65 + tid];
        Part[pbase + 4096 + tid] = s;
    }
}

// Fold 16 chunk-partials -> Ks fp32 + KVb bf16 in MFMA B-fragment order.
__global__ __launch_bounds__(256) void kv_pack(
        const float* __restrict__ Part, u16t* __restrict__ KVb,
        float* __restrict__ Ks) {
    __shared__ float kvs[64][64];
    const int bh = blockIdx.x;
    const int tid = threadIdx.x;
    const size_t base = (size_t)bh * 16 * 4160;
#pragma unroll
    for (int rr = 0; rr < 4; ++rr) {
        const int fi = rr * 256 + tid;       // 1024 float4s = 64x64
        const int d = fi >> 4;
        const int e4 = (fi & 15) * 4;
        float4 s = make_float4(0.f, 0.f, 0.f, 0.f);
        for (int c = 0; c < 16; ++c) {
            const float4 p =
                *(const float4*)&Part[base + (size_t)c * 4160 + d * 64 + e4];
            s.x += p.x; s.y += p.y; s.z += p.z; s.w += p.w;
        }
        *(float4*)&kvs[d][e4] = s;
    }
    if (tid < 64) {
        float s = 0.f;
        for (int c = 0; c < 16; ++c)
            s += Part[base + (size_t)c * 4160 + 4096 + tid];
        Ks[bh * 64 + tid] = s;
    }
    __syncthreads();
#pragma unroll
    for (int i = 0; i < 2; ++i) {
        const int c = tid + i * 256;
        const int ksi = c >> 8;
        const int nb = (c >> 6) & 3;
        const int L = c & 63;
        const int quad = L >> 4, l16 = L & 15;
        v8u pk;
#pragma unroll
        for (int j = 0; j < 8; ++j)
            pk[j] = f2bf(kvs[ksi * 32 + quad * 8 + j][nb * 16 + l16]);
        *(v8u*)&KVb[((size_t)bh * 512 + c) * 8] = pk;
    }
}

// attn = (Q @ KV) / (Q.Ksum + 1e-6), in-place over Q.  grid (512, 8).
__global__ __launch_bounds__(256) void attn_apply(
        u16t* __restrict__ Q, const u16t* __restrict__ KVb,
        const float* __restrict__ Ksum) {
    __shared__ u16t Qs[128][72];
    __shared__ float ksl[64];
    __shared__ float rden[128];
    const int bx = blockIdx.x;
    const int h = blockIdx.y;
    const int b = bx >> 6;
    const int bh = b * 8 + h;
    const int tid = threadIdx.x;
    const int w = tid >> 6, lane = tid & 63, quad = lane >> 4, l16 = lane & 15;
    const size_t row0 = (size_t)bx * 128;

#pragma unroll
    for (int i = 0; i < 4; ++i) {
        const int cid = tid + i * 256;
        const int r = cid >> 3;
        const int c8 = (cid & 7) * 8;
        *(uint4*)&Qs[r][c8] = *(const uint4*)&Q[(row0 + r) * 512 + h * 64 + c8];
    }
    if (tid < 64) ksl[tid] = Ksum[bh * 64 + tid];
    __syncthreads();

    if (tid < 128) {
        float a = 1e-6f;
#pragma unroll
        for (int d = 0; d < 64; ++d) a += bf2f(Qs[tid][d]) * ksl[d];
        rden[tid] = 1.0f / fmaxf(a, 1e-9f);
    }

    v8bf bfr[2][4];
#pragma unroll
    for (int ksi = 0; ksi < 2; ++ksi)
#pragma unroll
        for (int nb = 0; nb < 4; ++nb)
            bfr[ksi][nb] = *(const v8bf*)
                &KVb[((size_t)bh * 512 + ksi * 256 + nb * 64 + lane) * 8];
    __syncthreads();

    v4f acc[2][4];
#pragma unroll
    for (int i = 0; i < 2; ++i)
#pragma unroll
        for (int j = 0; j < 4; ++j) acc[i][j] = (v4f){0.f, 0.f, 0.f, 0.f};

#pragma unroll
    for (int ksi = 0; ksi < 2; ++ksi) {
        v8bf af[2];
#pragma unroll
        for (int mt = 0; mt < 2; ++mt)
            af[mt] = *(const v8bf*)&Qs[w * 32 + mt * 16 + l16][ksi * 32 + quad * 8];
#pragma unroll
        for (int mt = 0; mt < 2; ++mt)
#pragma unroll
            for (int nb = 0; nb < 4; ++nb)
                acc[mt][nb] = __builtin_amdgcn_mfma_f32_16x16x32_bf16(
                    af[mt], bfr[ksi][nb], acc[mt][nb], 0, 0, 0);
    }

    // restage scaled result through Qs -> coalesced uint4 stores
    __syncthreads();                     // all waves done reading Qs
#pragma unroll
    for (int mt = 0; mt < 2; ++mt)
#pragma unroll
        for (int nb = 0; nb < 4; ++nb)
#pragma unroll
            for (int r = 0; r < 4; ++r) {
                const int rl = w * 32 + mt * 16 + quad * 4 + r;
                const int e = nb * 16 + l16;
                Qs[rl][e] = f2bf(acc[mt][nb][r] * rden[rl]);
            }
    __syncthreads();
#pragma unroll
    for (int i = 0; i < 4; ++i) {
        const int f = i * 256 + tid;         // [0,1024): 128 rows x 8 slots
        const int row = f >> 3;
        const int c8 = (f & 7) * 8;
        *(uint4*)&Q[(row0 + row) * 512 + h * 64 + c8] =
            *(const uint4*)&Qs[row][c8];
    }
}

// ---------------------------------------------------------------------------
extern "C" void kernel_launch(void* const* d_in, const int* in_sizes, int n_in,
                              void* d_out, int out_size, void* d_ws, size_t ws_size,
                              hipStream_t stream) {
    (void)in_sizes; (void)n_in; (void)out_size; (void)ws_size;
    const float* x32  = (const float*)d_in[0];
    const float* Wq32 = (const float*)d_in[1];
    const float* bq32 = (const float*)d_in[2];
    const float* Wk32 = (const float*)d_in[3];
    const float* bk32 = (const float*)d_in[4];
    const float* Wv32 = (const float*)d_in[5];
    const float* bv32 = (const float*)d_in[6];
    const float* Wo32 = (const float*)d_in[7];
    const float* bo32 = (const float*)d_in[8];

    // d_out (128 MiB fp32) doubles as scratch: xb bf16 + Vb bf16.
    // After qkv_gemm, xb is dead; kv_reduce reuses its space for Part
    // (1024 x 65*64 fp32 = 17MB), read back by kv_pack before out_gemm.
    u16t* xb = (u16t*)d_out;
    u16t* Vb = (u16t*)d_out + (size_t)33554432;
    float* Part = (float*)d_out;

    char* ws = (char*)d_ws;
    const size_t SZ   = (size_t)65536 * 512 * sizeof(u16t);    // 64 MiB
    const size_t KSB  = (size_t)64 * 64 * 4;                   // 16 KiB
    const size_t KVbB = (size_t)64 * 512 * 16;                 // 512 KiB
    u16t*  Qb    = (u16t*)(ws);
    u16t*  Kb    = (u16t*)(ws + SZ);
    float* Ks    = (float*)(ws + 2 * SZ);
    u16t*  KVb   = (u16t*)(ws + 2 * SZ + KSB);
    u16t*  Wpack = (u16t*)(ws + 2 * SZ + KSB + KVbB);
    u16t*  bpack = Wpack + (size_t)4 * 262144;

    const dim3 blk(256);
    cvt_x <<<dim3(16384), blk, 0, stream>>>(x32, xb);
    cvt_wb<<<dim3(516),   blk, 0, stream>>>(Wq32, Wk32, Wv32, Wo32,
                                            bq32, bk32, bv32, bo32,
                                            Wpack, bpack);
    qkv_gemm  <<<dim3(6144),   blk, 0, stream>>>(xb, Wpack, bpack, Qb, Kb, Vb);
    kv_reduce <<<dim3(1024),   blk, 0, stream>>>(Kb, Vb, Part);
    kv_pack   <<<dim3(64),     blk, 0, stream>>>(Part, KVb, Ks);
    attn_apply<<<dim3(512, 8), blk, 0, stream>>>(Qb, KVb, Ks);
    out_gemm  <<<dim3(2048),   blk, 0, stream>>>(Qb, Wpack + 3 * 262144,
                                                 bpack + 3 * 512,
                                                 (float*)d_out);
}

// Round 4
// 494.337 us; speedup vs baseline: 1.2876x; 1.0338x over previous
//
#include <hip/hip_runtime.h>
#include <hip/hip_bf16.h>

// EfficientLinearAttention on MI355X (gfx950).
// B=8 T=8192 C=512 H=8 D=64.  M = B*T = 65536 rows.
// External tensors fp32, internal compute bf16, output fp32.
//
// Pipeline:
//   cvt_x    : x fp32 -> bf16 xb            (in d_out[0:64MiB))
//   cvt_wb   : Wq/Wk/Wv/Wo + biases -> bf16 Wpack/bpack (ws)
//   qkv_gemm : fused Q/K/V projection (3-buf counted-vmcnt pipeline)
//   kv_reduce: per-(bh,chunk) partial KV = K^T V + Ksum partial, NO atomics
//   kv_pack  : fold 16 chunk-partials, write Ks + bf16 KVb fragments
//   attn_apply: attn = (Q@KV)/(Q.Ksum+1e-6), in-place on ws.Qb
//   out_gemm : out = attn@Wo^T+bo -> d_out fp32
//
// R6 changes vs R5 (511 us, qkv_gemm 177 us = 582 TF = the 2-phase plateau):
//   * gemm_core: counted-vmcnt pipeline (T4).  __syncthreads drains vmcnt(0)
//     every K-step, serializing the prefetch; replaced with 3 LDS buffers,
//     prefetch distance 2, and per step:
//       ISSUE(kt+2) ; ds_read(kt%3)+MFMA ; s_waitcnt vmcnt(4) ; s_barrier
//     Each wave waits for ITS OWN tile-(kt+1) loads BEFORE the barrier, so
//     after the barrier all waves' loads landed (HK cross-wave pattern);
//     tile kt+2's loads stay in flight across the barrier (never vmcnt(0)
//     in the main loop).  One barrier per step (was 1 + full drain).
//   * LDS 32->48 KiB (3 blocks/CU, >= current effective occupancy).
//   * Everything else unchanged from R5 (verified): swizzled staging,
//     XCD remaps, LDS-staged epilogues, atomic-free kv_reduce.

typedef unsigned short u16t;
typedef unsigned int   u32t;
typedef __bf16 v8bf __attribute__((ext_vector_type(8)));
typedef u16t   v8u  __attribute__((ext_vector_type(8)));
typedef float  v4f  __attribute__((ext_vector_type(4)));

static __device__ __forceinline__ float bf2f(u16t b) {
    u32t u = ((u32t)b) << 16;
    return __builtin_bit_cast(float, u);
}
static __device__ __forceinline__ u16t f2bf(float f) {
    u32t u = __builtin_bit_cast(u32t, f);
    u += 0x7fffu + ((u >> 16) & 1u);   // round-to-nearest-even
    return (u16t)(u >> 16);
}
static __device__ __forceinline__ v8u cvt8(const float* p) {
    const float4 a = *(const float4*)p;
    const float4 b = *(const float4*)(p + 4);
    v8u r;
    r[0] = f2bf(a.x); r[1] = f2bf(a.y); r[2] = f2bf(a.z); r[3] = f2bf(a.w);
    r[4] = f2bf(b.x); r[5] = f2bf(b.y); r[6] = f2bf(b.z); r[7] = f2bf(b.w);
    return r;
}

// async global->LDS, 16B per lane; LDS dest must be base+lane*16 contiguous.
#define GLDS16(g, l) __builtin_amdgcn_global_load_lds(                       \
        (const __attribute__((address_space(1))) void*)(g),                  \
        (__attribute__((address_space(3))) void*)(l), 16, 0, 0)

// counted vmcnt wait (volatile asm = hard scheduling boundary for VMEM)
#define WAITV(N) asm volatile("s_waitcnt vmcnt(" #N ")" ::: "memory")
// raw barrier without the __syncthreads vmcnt(0) drain
#define BARRIER() do { __builtin_amdgcn_sched_barrier(0);                    \
                       __builtin_amdgcn_s_barrier();                         \
                       __builtin_amdgcn_sched_barrier(0); } while (0)

// ---------------------------------------------------------------------------
__global__ __launch_bounds__(256) void cvt_x(
        const float* __restrict__ src, u16t* __restrict__ dst) {
    const int i = (blockIdx.x * 256 + threadIdx.x) * 8;   // 16384 blocks
    *(v8u*)&dst[i] = cvt8(&src[i]);
}

__global__ __launch_bounds__(256) void cvt_wb(
        const float* __restrict__ Wq, const float* __restrict__ Wk,
        const float* __restrict__ Wv, const float* __restrict__ Wo,
        const float* __restrict__ bq, const float* __restrict__ bk,
        const float* __restrict__ bv, const float* __restrict__ bo,
        u16t* __restrict__ Wpack, u16t* __restrict__ bpack) {
    const int b = blockIdx.x;
    if (b < 512) {                       // 4 x 512x512 weights, 2048 elems/blk
        const int gidx = (b * 256 + threadIdx.x) * 8;     // [0, 1048576)
        const int seg = gidx >> 18;
        const int off = gidx & 262143;
        const float* src = (seg == 0) ? Wq : (seg == 1) ? Wk
                          : (seg == 2) ? Wv : Wo;
        *(v8u*)&Wpack[gidx] = cvt8(&src[off]);
    } else {                             // 4 biases of 512
        const int seg = b - 512;
        const float* src = (seg == 0) ? bq : (seg == 1) ? bk
                          : (seg == 2) ? bv : bo;
        if (threadIdx.x < 64) {
            const int off = threadIdx.x * 8;
            *(v8u*)&bpack[seg * 512 + off] = cvt8(&src[off]);
        }
    }
}

// ---------------------------------------------------------------------------
// Shared GEMM core: C_tile[128x128] = A[128xK] @ W[128xK]^T, K=512, bf16,
// fp32 accum.  4 waves in 2x2 grid, 64x64 per wave, 4x4 16x16x32 MFMA tiles.
//
// 3-buffer counted-vmcnt pipeline (see header).  LDS per buffer:
// A[128][32] (4096 elems) + B[128][32] at +4096; buffer b at sm + b*8192.
// Bank-conflict fix via XOR swizzle on the global SOURCE column
// (slot ^= (row>>1)&3), undone on the ds_read side (DMA dest stays linear).
// ---------------------------------------------------------------------------
static __device__ __forceinline__ void gemm_core(
        const u16t* __restrict__ A, const u16t* __restrict__ W,
        size_t mbase, int nbase, u16t* sm, v4f acc[4][4], int tid) {
    const int w    = tid >> 6;
    const int lane = tid & 63;
    const int quad = lane >> 4;
    const int l16  = lane & 15;
    const int wm   = (w & 1) * 64;
    const int wn   = (w >> 1) * 64;

#pragma unroll
    for (int i = 0; i < 4; ++i)
#pragma unroll
        for (int j = 0; j < 4; ++j) acc[i][j] = (v4f){0.f, 0.f, 0.f, 0.f};

    // DMA rows for this thread's two A-issues / two B-issues.
    const int r0 = w * 32 + (lane >> 2);
    const int r1 = r0 + 16;
    // swizzled source k-slot: LDS[r][s] ends up holding G[r][s ^ ((r>>1)&3)]
    // ((r>>1)&3 == (lane>>3)&3 for both r0 and r1).
    const int cs = ((lane & 3) ^ ((lane >> 3) & 3)) * 8;
    const u16t* pa0 = A + (mbase + r0) * 512 + cs;
    const u16t* pa1 = A + (mbase + r1) * 512 + cs;
    const u16t* pb0 = W + (size_t)(nbase + r0) * 512 + cs;
    const u16t* pb1 = W + (size_t)(nbase + r1) * 512 + cs;
    u16t* const la = sm + w * 1024 + lane * 8;          // A dest, buf 0
    u16t* const lb = sm + 4096 + w * 1024 + lane * 8;   // B dest, buf 0

#define GC_ISSUE(buf)                                                        \
    do {                                                                     \
        GLDS16(pa0, la + (buf) * 8192);                                      \
        GLDS16(pa1, la + (buf) * 8192 + 512);                                \
        GLDS16(pb0, lb + (buf) * 8192);                                      \
        GLDS16(pb1, lb + (buf) * 8192 + 512);                                \
        pa0 += 32; pa1 += 32; pb0 += 32; pb1 += 32;                          \
    } while (0)

    const int sA = (quad ^ ((l16 >> 1) & 3)) * 8;   // un-swizzle on read

#define GC_COMPUTE(RB)                                                       \
    do {                                                                     \
        const u16t* Ab_ = sm + (RB) * 8192;                                  \
        const u16t* Bb_ = Ab_ + 4096;                                        \
        v8bf af_[4], bf_[4];                                                 \
        _Pragma("unroll")                                                    \
        for (int mi = 0; mi < 4; ++mi)                                       \
            af_[mi] = *(const v8bf*)&Ab_[(wm + mi * 16 + l16) * 32 + sA];    \
        _Pragma("unroll")                                                    \
        for (int ni = 0; ni < 4; ++ni)                                       \
            bf_[ni] = *(const v8bf*)&Bb_[(wn + ni * 16 + l16) * 32 + sA];    \
        _Pragma("unroll")                                                    \
        for (int mi = 0; mi < 4; ++mi)                                       \
            _Pragma("unroll")                                                \
            for (int ni = 0; ni < 4; ++ni)                                   \
                acc[mi][ni] = __builtin_amdgcn_mfma_f32_16x16x32_bf16(       \
                    af_[mi], bf_[ni], acc[mi][ni], 0, 0, 0);                 \
    } while (0)

// one steady-state K-step: issue tile kt+2, compute tile kt, then wait for
// tile kt+1 (its 4 loads) leaving tile kt+2's 4 in flight, then barrier.
#define GC_STEP(RB, IB)                                                      \
    do { GC_ISSUE(IB); GC_COMPUTE(RB); WAITV(4); BARRIER(); } while (0)

    // prologue: tiles 0,1 in flight; wait tile 0, keep tile 1 flying
    GC_ISSUE(0); GC_ISSUE(1);
    WAITV(4); BARRIER();
    // steps kt = 0..13 (read kt%3, issue (kt+2)%3)
    GC_STEP(0, 2); GC_STEP(1, 0); GC_STEP(2, 1);
    GC_STEP(0, 2); GC_STEP(1, 0); GC_STEP(2, 1);
    GC_STEP(0, 2); GC_STEP(1, 0); GC_STEP(2, 1);
    GC_STEP(0, 2); GC_STEP(1, 0); GC_STEP(2, 1);
    GC_STEP(0, 2); GC_STEP(1, 0);
    // kt = 14: no issue; wait tile 15 fully (last outstanding)
    GC_COMPUTE(2); WAITV(0); BARRIER();
    // kt = 15
    GC_COMPUTE(0);
#undef GC_STEP
#undef GC_COMPUTE
#undef GC_ISSUE
}

// Fused Q/K/V projection.  1-D grid of 6144 blocks, XCD-bijective remap:
// wg = (id%8)*768 + id/8 -> each XCD owns 64 contiguous m-tiles and the 12
// (p,n)-blocks of one m-tile are consecutive on that XCD (A-tile L2 reuse).
__global__ __launch_bounds__(256) void qkv_gemm(
        const u16t* __restrict__ xb, const u16t* __restrict__ Wpack,
        const u16t* __restrict__ bpack,
        u16t* __restrict__ Qb, u16t* __restrict__ Kb, u16t* __restrict__ Vb) {
    __shared__ __align__(16) u16t sm[24576];   // 48KiB: 3 bufs / Cs[64][132]
    const u32t id = blockIdx.x;
    const u32t wg = (id & 7) * 768 + (id >> 3);
    const int sub = (int)(wg % 12u);
    const int p = sub >> 2;
    const int nbase = (sub & 3) * 128;
    const size_t mbase = (size_t)(wg / 12u) * 128;
    const u16t* W = Wpack + (size_t)p * 262144;
    const u16t* bias = bpack + p * 512;
    u16t* C = (p == 0) ? Qb : (p == 1) ? Kb : Vb;
    const bool elu = (p < 2);
    const int tid = threadIdx.x;
    const int w = tid >> 6, lane = tid & 63, quad = lane >> 4, l16 = lane & 15;
    const int wn = (w >> 1) * 64;

    v4f acc[4][4];
    gemm_core(xb, W, mbase, nbase, sm, acc, tid);
    __syncthreads();                     // all reads of sm done -> reuse

    // Epilogue: two 64-row passes through LDS -> 16B/lane coalesced stores.
    u16t (*Cs)[132] = (u16t(*)[132])sm;
#pragma unroll
    for (int pass = 0; pass < 2; ++pass) {
        if ((w & 1) == pass) {           // waves owning rows [pass*64, +64)
#pragma unroll
            for (int ni = 0; ni < 4; ++ni) {
                const int lcol = wn + ni * 16 + l16;
                const float bb = bf2f(bias[nbase + lcol]);
#pragma unroll
                for (int mi = 0; mi < 4; ++mi)
#pragma unroll
                    for (int r = 0; r < 4; ++r) {
                        float v = acc[mi][ni][r] + bb;
                        if (elu) v = (v > 0.f) ? (v + 1.f) : __expf(v);
                        Cs[mi * 16 + quad * 4 + r][lcol] = f2bf(v);
                    }
            }
        }
        __syncthreads();
#pragma unroll
        for (int rep = 0; rep < 4; ++rep) {
            const int f = rep * 256 + tid;   // [0,1024): 64 rows x 16 8-slots
            const int row = f >> 4;
            const int c8 = (f & 15) * 8;
            const uint2 lo = *(const uint2*)&Cs[row][c8];
            const uint2 hi = *(const uint2*)&Cs[row][c8 + 4];
            const uint4 val = make_uint4(lo.x, lo.y, hi.x, hi.y);
            *(uint4*)&C[(mbase + pass * 64 + row) * 512 + nbase + c8] = val;
        }
        __syncthreads();
    }
}

// out = attn @ Wo^T + bo, fp32 out.  1-D grid of 2048 blocks, XCD remap.
__global__ __launch_bounds__(256) void out_gemm(
        const u16t* __restrict__ attn, const u16t* __restrict__ Wo,
        const u16t* __restrict__ bo, float* __restrict__ C) {
    __shared__ __align__(16) u16t sm[24576];   // 48KiB: 3 bufs / Cf[32][132]
    const u32t id = blockIdx.x;
    const u32t wg = (id & 7) * 256 + (id >> 3);
    const int nbase = (int)(wg & 3u) * 128;
    const size_t mbase = (size_t)(wg >> 2) * 128;
    const int tid = threadIdx.x;
    const int w = tid >> 6, lane = tid & 63, quad = lane >> 4, l16 = lane & 15;
    const int wn = (w >> 1) * 64;

    v4f acc[4][4];
    gemm_core(attn, Wo, mbase, nbase, sm, acc, tid);
    __syncthreads();                     // all reads of sm done -> reuse

    // fp32 tile staged + stored in four 32-row passes of 16.5KiB.
    float (*Cf)[132] = (float(*)[132])sm;
#pragma unroll
    for (int p = 0; p < 4; ++p) {
        if ((w & 1) == (p >> 1)) {       // waves owning rows [p*32, +32)
#pragma unroll
            for (int ni = 0; ni < 4; ++ni) {
                const int lcol = wn + ni * 16 + l16;
                const float bb = bf2f(bo[nbase + lcol]);
#pragma unroll
                for (int m2 = 0; m2 < 2; ++m2) {
                    const int mi = (p & 1) * 2 + m2;
#pragma unroll
                    for (int r = 0; r < 4; ++r)
                        Cf[m2 * 16 + quad * 4 + r][lcol] = acc[mi][ni][r] + bb;
                }
            }
        }
        __syncthreads();
#pragma unroll
        for (int rep = 0; rep < 4; ++rep) {
            const int f = rep * 256 + tid;   // [0,1024): 32 rows x 32 f4slots
            const int row = f >> 5;
            const int c4 = (f & 31) * 4;
            *(float4*)&C[(mbase + p * 32 + row) * 512 + nbase + c4] =
                *(const float4*)&Cf[row][c4];
        }
        __syncthreads();
    }
}

// ---------------------------------------------------------------------------
// Partial KV: Part[bh*16+chunk] = [65][64] fp32; rows 0..63 = K^T V over the
// chunk's 512 t-rows, row 64 = Ksum partial.  NO atomics.
// 1-D grid 1024 blocks, XCD-bijective remap: batch b -> XCD b, the 8
// h-blocks of one (b,chunk) adjacent in dispatch (row locality).
// ---------------------------------------------------------------------------
__global__ __launch_bounds__(256) void kv_reduce(
        const u16t* __restrict__ Kp, const u16t* __restrict__ Vp,
        float* __restrict__ Part) {
    __shared__ u16t Kl[64][66];
    __shared__ u16t Vl[64][66];
    const u32t id  = blockIdx.x;                   // [0,1024)
    const u32t swz = (id & 7) * 128 + (id >> 3);   // bijective
    const int h     = (int)(swz & 7);
    const int grp   = (int)(swz >> 3);             // b*16 + chunk
    const int b     = grp >> 4;
    const int chunk = grp & 15;
    const int bh    = b * 8 + h;
    const int tid = threadIdx.x;
    const int w = tid >> 6, lane = tid & 63, quad = lane >> 4, l16 = lane & 15;
    const int trow0 = tid >> 3;                    // 0..31
    const int c8 = (tid & 7) * 8;

    v4f acc[4];
#pragma unroll
    for (int i = 0; i < 4; ++i) acc[i] = (v4f){0.f, 0.f, 0.f, 0.f};
    float ks[8];
#pragma unroll
    for (int j = 0; j < 8; ++j) ks[j] = 0.f;

    size_t g0 = ((size_t)b * 8192 + chunk * 512 + trow0) * 512 + h * 64 + c8;
    size_t g1 = g0 + 32 * 512;
    uint4 kq0 = *(const uint4*)&Kp[g0];
    uint4 kq1 = *(const uint4*)&Kp[g1];
    uint4 vq0 = *(const uint4*)&Vp[g0];
    uint4 vq1 = *(const uint4*)&Vp[g1];

    for (int tile = 0; tile < 8; ++tile) {
        // stage current regs to LDS, fold Ksum
        *(u32t*)&Kl[trow0][c8 + 0] = kq0.x;
        *(u32t*)&Kl[trow0][c8 + 2] = kq0.y;
        *(u32t*)&Kl[trow0][c8 + 4] = kq0.z;
        *(u32t*)&Kl[trow0][c8 + 6] = kq0.w;
        *(u32t*)&Kl[trow0 + 32][c8 + 0] = kq1.x;
        *(u32t*)&Kl[trow0 + 32][c8 + 2] = kq1.y;
        *(u32t*)&Kl[trow0 + 32][c8 + 4] = kq1.z;
        *(u32t*)&Kl[trow0 + 32][c8 + 6] = kq1.w;
        *(u32t*)&Vl[trow0][c8 + 0] = vq0.x;
        *(u32t*)&Vl[trow0][c8 + 2] = vq0.y;
        *(u32t*)&Vl[trow0][c8 + 4] = vq0.z;
        *(u32t*)&Vl[trow0][c8 + 6] = vq0.w;
        *(u32t*)&Vl[trow0 + 32][c8 + 0] = vq1.x;
        *(u32t*)&Vl[trow0 + 32][c8 + 2] = vq1.y;
        *(u32t*)&Vl[trow0 + 32][c8 + 4] = vq1.z;
        *(u32t*)&Vl[trow0 + 32][c8 + 6] = vq1.w;
        {
            const v8u ku0 = __builtin_bit_cast(v8u, kq0);
            const v8u ku1 = __builtin_bit_cast(v8u, kq1);
#pragma unroll
            for (int j = 0; j < 8; ++j)
                ks[j] += bf2f(ku0[j]) + bf2f(ku1[j]);
        }
        __syncthreads();
        // issue next tile's loads now: the end-of-tile barrier's vmcnt
        // drain is then covered by the LDS-read + MFMA phase below.
        if (tile < 7) {
            g0 += 64 * 512; g1 += 64 * 512;
            kq0 = *(const uint4*)&Kp[g0];
            kq1 = *(const uint4*)&Kp[g1];
            vq0 = *(const uint4*)&Vp[g0];
            vq1 = *(const uint4*)&Vp[g1];
        }
#pragma unroll
        for (int ts = 0; ts < 2; ++ts) {
            v8u au;
#pragma unroll
            for (int j = 0; j < 8; ++j)
                au[j] = Kl[ts * 32 + quad * 8 + j][w * 16 + l16];
            const v8bf af = __builtin_bit_cast(v8bf, au);
#pragma unroll
            for (int et = 0; et < 4; ++et) {
                v8u bu;
#pragma unroll
                for (int j = 0; j < 8; ++j)
                    bu[j] = Vl[ts * 32 + quad * 8 + j][et * 16 + l16];
                acc[et] = __builtin_amdgcn_mfma_f32_16x16x32_bf16(
                    af, __builtin_bit_cast(v8bf, bu), acc[et], 0, 0, 0);
            }
        }
        __syncthreads();
    }

    // store partial KV tile (plain coalesced stores)
    const size_t pbase = (size_t)(bh * 16 + chunk) * 4160;   // 65*64
#pragma unroll
    for (int et = 0; et < 4; ++et)
#pragma unroll
        for (int r = 0; r < 4; ++r)
            Part[pbase + (size_t)(w * 16 + quad * 4 + r) * 64 + et * 16 + l16]
                = acc[et][r];

    // Ksum partial: LDS tree (reuse Kl as float [32][65], 8320B <= 8448B)
    float* kr = (float*)&Kl[0][0];
#pragma unroll
    for (int j = 0; j < 8; ++j) kr[trow0 * 65 + c8 + j] = ks[j];
    __syncthreads();
    if (tid < 64) {
        float s = 0.f;
#pragma unroll
        for (int g = 0; g < 32; ++g) s += kr[g * 65 + tid];
        Part[pbase + 4096 + tid] = s;
    }
}

// Fold 16 chunk-partials -> Ks fp32 + KVb bf16 in MFMA B-fragment order.
__global__ __launch_bounds__(256) void kv_pack(
        const float* __restrict__ Part, u16t* __restrict__ KVb,
        float* __restrict__ Ks) {
    __shared__ float kvs[64][64];
    const int bh = blockIdx.x;
    const int tid = threadIdx.x;
    const size_t base = (size_t)bh * 16 * 4160;
#pragma unroll
    for (int rr = 0; rr < 4; ++rr) {
        const int fi = rr * 256 + tid;       // 1024 float4s = 64x64
        const int d = fi >> 4;
        const int e4 = (fi & 15) * 4;
        float4 s = make_float4(0.f, 0.f, 0.f, 0.f);
        for (int c = 0; c < 16; ++c) {
            const float4 p =
                *(const float4*)&Part[base + (size_t)c * 4160 + d * 64 + e4];
            s.x += p.x; s.y += p.y; s.z += p.z; s.w += p.w;
        }
        *(float4*)&kvs[d][e4] = s;
    }
    if (tid < 64) {
        float s = 0.f;
        for (int c = 0; c < 16; ++c)
            s += Part[base + (size_t)c * 4160 + 4096 + tid];
        Ks[bh * 64 + tid] = s;
    }
    __syncthreads();
#pragma unroll
    for (int i = 0; i < 2; ++i) {
        const int c = tid + i * 256;
        const int ksi = c >> 8;
        const int nb = (c >> 6) & 3;
        const int L = c & 63;
        const int quad = L >> 4, l16 = L & 15;
        v8u pk;
#pragma unroll
        for (int j = 0; j < 8; ++j)
            pk[j] = f2bf(kvs[ksi * 32 + quad * 8 + j][nb * 16 + l16]);
        *(v8u*)&KVb[((size_t)bh * 512 + c) * 8] = pk;
    }
}

// attn = (Q @ KV) / (Q.Ksum + 1e-6), in-place over Q.  grid (512, 8).
__global__ __launch_bounds__(256) void attn_apply(
        u16t* __restrict__ Q, const u16t* __restrict__ KVb,
        const float* __restrict__ Ksum) {
    __shared__ u16t Qs[128][72];
    __shared__ float ksl[64];
    __shared__ float rden[128];
    const int bx = blockIdx.x;
    const int h = blockIdx.y;
    const int b = bx >> 6;
    const int bh = b * 8 + h;
    const int tid = threadIdx.x;
    const int w = tid >> 6, lane = tid & 63, quad = lane >> 4, l16 = lane & 15;
    const size_t row0 = (size_t)bx * 128;

#pragma unroll
    for (int i = 0; i < 4; ++i) {
        const int cid = tid + i * 256;
        const int r = cid >> 3;
        const int c8 = (cid & 7) * 8;
        *(uint4*)&Qs[r][c8] = *(const uint4*)&Q[(row0 + r) * 512 + h * 64 + c8];
    }
    if (tid < 64) ksl[tid] = Ksum[bh * 64 + tid];
    __syncthreads();

    if (tid < 128) {
        float a = 1e-6f;
#pragma unroll
        for (int d = 0; d < 64; ++d) a += bf2f(Qs[tid][d]) * ksl[d];
        rden[tid] = 1.0f / fmaxf(a, 1e-9f);
    }

    v8bf bfr[2][4];
#pragma unroll
    for (int ksi = 0; ksi < 2; ++ksi)
#pragma unroll
        for (int nb = 0; nb < 4; ++nb)
            bfr[ksi][nb] = *(const v8bf*)
                &KVb[((size_t)bh * 512 + ksi * 256 + nb * 64 + lane) * 8];
    __syncthreads();

    v4f acc[2][4];
#pragma unroll
    for (int i = 0; i < 2; ++i)
#pragma unroll
        for (int j = 0; j < 4; ++j) acc[i][j] = (v4f){0.f, 0.f, 0.f, 0.f};

#pragma unroll
    for (int ksi = 0; ksi < 2; ++ksi) {
        v8bf af[2];
#pragma unroll
        for (int mt = 0; mt < 2; ++mt)
            af[mt] = *(const v8bf*)&Qs[w * 32 + mt * 16 + l16][ksi * 32 + quad * 8];
#pragma unroll
        for (int mt = 0; mt < 2; ++mt)
#pragma unroll
            for (int nb = 0; nb < 4; ++nb)
                acc[mt][nb] = __builtin_amdgcn_mfma_f32_16x16x32_bf16(
                    af[mt], bfr[ksi][nb], acc[mt][nb], 0, 0, 0);
    }

    // restage scaled result through Qs -> coalesced uint4 stores
    __syncthreads();                     // all waves done reading Qs
#pragma unroll
    for (int mt = 0; mt < 2; ++mt)
#pragma unroll
        for (int nb = 0; nb < 4; ++nb)
#pragma unroll
            for (int r = 0; r < 4; ++r) {
                const int rl = w * 32 + mt * 16 + quad * 4 + r;
                const int e = nb * 16 + l16;
                Qs[rl][e] = f2bf(acc[mt][nb][r] * rden[rl]);
            }
    __syncthreads();
#pragma unroll
    for (int i = 0; i < 4; ++i) {
        const int f = i * 256 + tid;         // [0,1024): 128 rows x 8 slots
        const int row = f >> 3;
        const int c8 = (f & 7) * 8;
        *(uint4*)&Q[(row0 + row) * 512 + h * 64 + c8] =
            *(const uint4*)&Qs[row][c8];
    }
}

// ---------------------------------------------------------------------------
extern "C" void kernel_launch(void* const* d_in, const int* in_sizes, int n_in,
                              void* d_out, int out_size, void* d_ws, size_t ws_size,
                              hipStream_t stream) {
    (void)in_sizes; (void)n_in; (void)out_size; (void)ws_size;
    const float* x32  = (const float*)d_in[0];
    const float* Wq32 = (const float*)d_in[1];
    const float* bq32 = (const float*)d_in[2];
    const float* Wk32 = (const float*)d_in[3];
    const float* bk32 = (const float*)d_in[4];
    const float* Wv32 = (const float*)d_in[5];
    const float* bv32 = (const float*)d_in[6];
    const float* Wo32 = (const float*)d_in[7];
    const float* bo32 = (const float*)d_in[8];

    // d_out (128 MiB fp32) doubles as scratch: xb bf16 + Vb bf16.
    // After qkv_gemm, xb is dead; kv_reduce reuses its space for Part
    // (1024 x 65*64 fp32 = 17MB), read back by kv_pack before out_gemm.
    u16t* xb = (u16t*)d_out;
    u16t* Vb = (u16t*)d_out + (size_t)33554432;
    float* Part = (float*)d_out;

    char* ws = (char*)d_ws;
    const size_t SZ   = (size_t)65536 * 512 * sizeof(u16t);    // 64 MiB
    const size_t KSB  = (size_t)64 * 64 * 4;                   // 16 KiB
    const size_t KVbB = (size_t)64 * 512 * 16;                 // 512 KiB
    u16t*  Qb    = (u16t*)(ws);
    u16t*  Kb    = (u16t*)(ws + SZ);
    float* Ks    = (float*)(ws + 2 * SZ);
    u16t*  KVb   = (u16t*)(ws + 2 * SZ + KSB);
    u16t*  Wpack = (u16t*)(ws + 2 * SZ + KSB + KVbB);
    u16t*  bpack = Wpack + (size_t)4 * 262144;

    const dim3 blk(256);
    cvt_x <<<dim3(16384), blk, 0, stream>>>(x32, xb);
    cvt_wb<<<dim3(516),   blk, 0, stream>>>(Wq32, Wk32, Wv32, Wo32,
                                            bq32, bk32, bv32, bo32,
                                            Wpack, bpack);
    qkv_gemm  <<<dim3(6144),   blk, 0, stream>>>(xb, Wpack, bpack, Qb, Kb, Vb);
    kv_reduce <<<dim3(1024),   blk, 0, stream>>>(Kb, Vb, Part);
    kv_pack   <<<dim3(64),     blk, 0, stream>>>(Part, KVb, Ks);
    attn_apply<<<dim3(512, 8), blk, 0, stream>>>(Qb, KVb, Ks);
    out_gemm  <<<dim3(2048),   blk, 0, stream>>>(Qb, Wpack + 3 * 262144,
                                                 bpack + 3 * 512,
                                                 (float*)d_out);
}